// Round 1
// baseline (4268.702 us; speedup 1.0000x reference)
//
#include <hip/hip_runtime.h>
#include <hip/hip_bf16.h>

// EntropyResidualBlock: y1 = prelu(maskconv(x,w1)+b1); y2 = prelu(maskconv(y1,w2)+b2); out = y2 + x
// Mask keeps 13 taps: (kh=0,kw=0..4), (kh=1,kw=0..4), (2,0), (2,1), (2,2 group-causal i/24<=o/24).
// Strategy: implicit GEMM over taps with bf16 MFMA 16x16x32.
//   conv1: D[p][o] = sum_t sum_i X[p+d(t)][i] * W1[t][i][o]   (A=X, B=W)
//   conv2: D[o][p] = sum_t sum_i W2[t][o][i] * Y[p+d(t)][i]   (A=W, B=Y)
// Layouts: X,Y in NHWC bf16; weights repacked [t][o][i] bf16 (masked).
// d_out's first half is used as scratch for Xc (bf16 NHWC) — dead before conv2 writes d_out.
// ws layout: [ Y : 201326592 B ][ Wp1 : 3833856 B ][ Wp2 : 3833856 B ]  (total ~209 MB)

#define C_CH 384
#define HH   256
#define WWD  512
#define NN   2
#define NTAP 13

typedef __attribute__((ext_vector_type(8))) short short8;
typedef __attribute__((ext_vector_type(4))) float f32x4;
typedef __attribute__((ext_vector_type(4))) int  int4v;

__device__ inline unsigned short f2bf(float f) {
    union { float f; unsigned int u; } v; v.f = f;
    unsigned int r = v.u + 0x7FFFu + ((v.u >> 16) & 1u);
    return (unsigned short)(r >> 16);
}

// ---------------- weight repack + mask -> bf16 [t][o][i] ----------------
__global__ __launch_bounds__(256) void k_prepack(const float* __restrict__ w1, const float* __restrict__ w2,
                                                 unsigned short* __restrict__ wp1, unsigned short* __restrict__ wp2) {
    int idx = blockIdx.x * 256 + threadIdx.x;
    const int TOT = NTAP * C_CH * C_CH;
    if (idx >= TOT) return;
    int t = idx / (C_CH * C_CH);
    int rem = idx - t * C_CH * C_CH;
    int o = rem / C_CH;
    int i = rem - o * C_CH;
    int kh = t < 5 ? 0 : (t < 10 ? 1 : 2);
    int kw = t < 5 ? t : (t < 10 ? t - 5 : t - 10);
    bool keep = (t != 12) || ((i / 24) <= (o / 24));
    int src = ((o * C_CH + i) * 5 + kh) * 5 + kw;
    wp1[idx] = keep ? f2bf(w1[src]) : (unsigned short)0;
    wp2[idx] = keep ? f2bf(w2[src]) : (unsigned short)0;
}

// ---------------- x NCHW fp32 -> NHWC bf16 ----------------
__global__ __launch_bounds__(256) void k_tobf16_nhwc(const float* __restrict__ x, unsigned short* __restrict__ xc) {
    int bid = blockIdx.x;              // 2*256*8 = 4096 blocks, each 64 w x 384 c for one (n,h)
    int w0 = (bid & 7) << 6;
    int h  = (bid >> 3) & 255;
    int n  = bid >> 11;
    int wi = threadIdx.x & 63;
    int cq = threadIdx.x >> 6;         // 0..3
    int w  = w0 + wi;
    int pos = (n * HH + h) * WWD + w;
    int inb = n * C_CH * HH * WWD + h * WWD + w;
    for (int cc = 0; cc < 12; ++cc) {
        int c0 = cc * 32 + cq * 8;
        short8 outv;
        #pragma unroll
        for (int k = 0; k < 8; ++k) {
            float f = x[inb + (c0 + k) * (HH * WWD)];
            outv[k] = (short)f2bf(f);
        }
        *(short8*)&xc[pos * C_CH + c0] = outv;
    }
}

// ---------------- masked conv via MFMA ----------------
// block: 256 threads (4 waves, 2x2), tile 128 positions x 128 out-channels
// grid: 6144 = (N*H*(W/128)) * 3
template<int SECOND>
__global__ __launch_bounds__(256) void k_conv(const unsigned short* __restrict__ in_nhwc,
                                              const unsigned short* __restrict__ wp,
                                              const float* __restrict__ bias,
                                              const float* __restrict__ alpha,
                                              const float* __restrict__ xres,
                                              void* __restrict__ outp) {
    __shared__ __align__(16) unsigned short Xs[3 * 132 * 40];   // rows x cols x (32 ch padded to 40)
    __shared__ __align__(16) unsigned short Wsm[128 * 40];      // 128 o x (32 ch padded to 40)

    int bid = blockIdx.x;
    int ob = bid % 3;
    int sb = bid / 3;
    int wseg = sb & 3;
    int h = (sb >> 2) & 255;
    int n = sb >> 10;
    int w0 = wseg << 7;
    int o0 = ob << 7;

    int tid = threadIdx.x;
    int lane = tid & 63;
    int wv = tid >> 6;
    int wr = wv >> 1, wc = wv & 1;
    int lg = lane >> 4, lm = lane & 15;

    f32x4 acc[4][4];
    #pragma unroll
    for (int i = 0; i < 4; ++i)
        #pragma unroll
        for (int j = 0; j < 4; ++j) acc[i][j] = (f32x4){0.f, 0.f, 0.f, 0.f};

    int pos_row = (n * HH + h) * WWD;

    for (int ic = 0; ic < 12; ++ic) {
        __syncthreads();   // previous iteration's Xs readers done
        // stage X tile: 3 rows x 132 cols x 32 ch (16B quads), zero-fill OOB
        for (int ci = tid; ci < 3 * 132 * 4; ci += 256) {
            int r = ci / 528;
            int rem = ci - r * 528;
            int c = rem >> 2, q = rem & 3;
            int hh2 = h + r - 2;
            int ww2 = w0 + c - 2;
            int4v v = (int4v){0, 0, 0, 0};
            if ((unsigned)hh2 < HH && (unsigned)ww2 < WWD) {
                v = *(const int4v*)&in_nhwc[((n * HH + hh2) * WWD + ww2) * C_CH + ic * 32 + q * 8];
            }
            *(int4v*)&Xs[r * 5280 + c * 40 + q * 8] = v;
        }
        for (int t = 0; t < NTAP; ++t) {
            __syncthreads();   // previous Wsm readers done (t==0: also fences Xs staging)
            for (int ci = tid; ci < 512; ci += 256) {
                int o = ci >> 2, q = ci & 3;
                *(int4v*)&Wsm[o * 40 + q * 8] =
                    *(const int4v*)&wp[(t * C_CH + (o0 + o)) * C_CH + ic * 32 + q * 8];
            }
            __syncthreads();   // staging visible
            int kh = t < 5 ? 0 : (t < 10 ? 1 : 2);
            int kw = t < 5 ? t : (t < 10 ? t - 5 : t - 10);
            short8 xa[4], wb[4];
            #pragma unroll
            for (int f = 0; f < 4; ++f) {
                int cidx = wr * 64 + f * 16 + lm + kw;
                xa[f] = *(const short8*)&Xs[kh * 5280 + cidx * 40 + lg * 8];
                wb[f] = *(const short8*)&Wsm[(wc * 64 + f * 16 + lm) * 40 + lg * 8];
            }
            #pragma unroll
            for (int i = 0; i < 4; ++i)
                #pragma unroll
                for (int j = 0; j < 4; ++j) {
                    if (SECOND)
                        acc[i][j] = __builtin_amdgcn_mfma_f32_16x16x32_bf16(wb[i], xa[j], acc[i][j], 0, 0, 0);
                    else
                        acc[i][j] = __builtin_amdgcn_mfma_f32_16x16x32_bf16(xa[i], wb[j], acc[i][j], 0, 0, 0);
                }
        }
    }

    if (!SECOND) {
        // D[p][o]: p = wr*64 + i*16 + lg*4 + r ; o = o0 + wc*64 + j*16 + lm
        unsigned short* y = (unsigned short*)outp;
        #pragma unroll
        for (int j = 0; j < 4; ++j) {
            int o = o0 + wc * 64 + j * 16 + lm;
            float bo = bias[o], ao = alpha[o];
            #pragma unroll
            for (int i = 0; i < 4; ++i) {
                #pragma unroll
                for (int r = 0; r < 4; ++r) {
                    int p = w0 + wr * 64 + i * 16 + lg * 4 + r;
                    float v = acc[i][j][r] + bo;
                    v = v >= 0.f ? v : ao * v;
                    y[(pos_row + p) * C_CH + o] = f2bf(v);
                }
            }
        }
    } else {
        // D[o][p]: o = o0 + wc*64 + i*16 + lg*4 + r ; w = w0 + wr*64 + j*16 + lm
        float* outf = (float*)outp;
        #pragma unroll
        for (int i = 0; i < 4; ++i) {
            #pragma unroll
            for (int r = 0; r < 4; ++r) {
                int o = o0 + wc * 64 + i * 16 + lg * 4 + r;
                float bo = bias[o], ao = alpha[o];
                #pragma unroll
                for (int j = 0; j < 4; ++j) {
                    int w = w0 + wr * 64 + j * 16 + lm;
                    float v = acc[i][j][r] + bo;
                    v = v >= 0.f ? v : ao * v;
                    int idx = ((n * C_CH + o) * HH + h) * WWD + w;
                    outf[idx] = v + xres[idx];
                }
            }
        }
    }
}

extern "C" void kernel_launch(void* const* d_in, const int* in_sizes, int n_in,
                              void* d_out, int out_size, void* d_ws, size_t ws_size,
                              hipStream_t stream) {
    const float* x  = (const float*)d_in[0];
    const float* w1 = (const float*)d_in[1];
    const float* b1 = (const float*)d_in[2];
    const float* a1 = (const float*)d_in[3];
    const float* w2 = (const float*)d_in[4];
    const float* b2 = (const float*)d_in[5];
    const float* a2 = (const float*)d_in[6];

    // scratch layout
    unsigned short* xc  = (unsigned short*)d_out;                       // 201,326,592 B (first half of d_out)
    unsigned short* y   = (unsigned short*)d_ws;                        // 201,326,592 B
    unsigned short* wp1 = (unsigned short*)((char*)d_ws + 201326592u);  // 3,833,856 B
    unsigned short* wp2 = wp1 + NTAP * C_CH * C_CH;                     // 3,833,856 B
    // requires ws_size >= 208,994,304 B

    k_prepack<<<(NTAP * C_CH * C_CH + 255) / 256, 256, 0, stream>>>(w1, w2, wp1, wp2);
    k_tobf16_nhwc<<<NN * HH * (WWD / 64), 256, 0, stream>>>(x, xc);
    k_conv<0><<<NN * HH * (WWD / 128) * 3, 256, 0, stream>>>(xc, wp1, b1, a1, nullptr, (void*)y);
    k_conv<1><<<NN * HH * (WWD / 128) * 3, 256, 0, stream>>>(y, wp2, b2, a2, x, (void*)d_out);
}

// Round 2
// 3277.437 us; speedup vs baseline: 1.3025x; 1.3025x over previous
//
#include <hip/hip_runtime.h>
#include <hip/hip_bf16.h>

// EntropyResidualBlock: y1 = prelu(maskconv(x,w1)+b1); y2 = prelu(maskconv(y1,w2)+b2); out = y2 + x
// 13 live taps: (0,kw0..4),(1,kw0..4),(2,0),(2,1),(2,2 group-causal i/24<=o/24).
// Implicit GEMM, mfma_f32_16x16x32_bf16.
//   conv1: D[p][o] = sum_t,i X[p+d(t)][i] * W1[t][i][o]   (A=X, B=W)
//   conv2: D[o][p] = sum_t,i W2[t][o][i] * Y[p+d(t)][i]   (A=W, B=Y)
// Round-2 structure: block = 2 h-rows x 128 w x 128 o, 4 waves (wr=row, wc=o-half),
// per-wave acc[8][4] (128p x 64o) -> 32 MFMA per 12 fragment-loads.
// X tile in LDS, XOR-swizzled (byte ^= (col&7)<<4), 33.8KB -> 2 blocks/CU.
// W loaded per-fragment straight from global (repacked [t][ic][o][32] -> coalesced 1KB/wave),
// so only 2 barriers per ic chunk.
// d_out first half = Xc scratch (dead before conv2 writes d_out).
// ws: [ Y : 201326592 B ][ Wp1 : 3833856 B ][ Wp2 : 3833856 B ]

#define C_CH 384
#define HH   256
#define WWD  512
#define NN   2

typedef __attribute__((ext_vector_type(8))) short short8;
typedef __attribute__((ext_vector_type(4))) float f32x4;
typedef __attribute__((ext_vector_type(4))) int  int4v;

__device__ inline unsigned short f2bf(float f) {
    union { float f; unsigned int u; } v; v.f = f;
    unsigned int r = v.u + 0x7FFFu + ((v.u >> 16) & 1u);
    return (unsigned short)(r >> 16);
}

// ---------------- weights -> bf16 wp[t][ic][o][iq], masked ----------------
__global__ __launch_bounds__(256) void k_prepack(const float* __restrict__ w1, const float* __restrict__ w2,
                                                 unsigned short* __restrict__ wp1, unsigned short* __restrict__ wp2) {
    int idx = blockIdx.x * 256 + threadIdx.x;
    const int TOT = 13 * 12 * C_CH * 32;
    if (idx >= TOT) return;
    int iq = idx & 31;
    int o  = (idx >> 5) % C_CH;
    int ic = (idx / (32 * C_CH)) % 12;
    int t  = idx / (32 * C_CH * 12);
    int i  = ic * 32 + iq;
    int kh = t < 5 ? 0 : (t < 10 ? 1 : 2);
    int kw = t < 5 ? t : (t < 10 ? t - 5 : t - 10);
    bool keep = (t != 12) || ((i / 24) <= (o / 24));
    int src = ((o * C_CH + i) * 5 + kh) * 5 + kw;
    wp1[idx] = keep ? f2bf(w1[src]) : (unsigned short)0;
    wp2[idx] = keep ? f2bf(w2[src]) : (unsigned short)0;
}

// ---------------- x NCHW fp32 -> NHWC bf16 ----------------
__global__ __launch_bounds__(256) void k_tobf16_nhwc(const float* __restrict__ x, unsigned short* __restrict__ xc) {
    int bid = blockIdx.x;              // 2*256*8 = 4096 blocks, each 64 w x 384 c for one (n,h)
    int w0 = (bid & 7) << 6;
    int h  = (bid >> 3) & 255;
    int n  = bid >> 11;
    int wi = threadIdx.x & 63;
    int cq = threadIdx.x >> 6;         // 0..3
    int w  = w0 + wi;
    int pos = (n * HH + h) * WWD + w;
    int inb = n * C_CH * HH * WWD + h * WWD + w;
    for (int cc = 0; cc < 12; ++cc) {
        int c0 = cc * 32 + cq * 8;
        short8 outv;
        #pragma unroll
        for (int k = 0; k < 8; ++k) {
            float f = x[inb + (c0 + k) * (HH * WWD)];
            outv[k] = (short)f2bf(f);
        }
        *(short8*)&xc[pos * C_CH + c0] = outv;
    }
}

// ---------------- masked conv via MFMA ----------------
// grid 3072 = n(2) x hpair(128) x wseg(4) x ob(3); 256 threads / 4 waves.
template<int SECOND>
__global__ __launch_bounds__(256, 2) void k_conv(const unsigned short* __restrict__ in_nhwc,
                                                 const unsigned short* __restrict__ wp,
                                                 const float* __restrict__ bias,
                                                 const float* __restrict__ alpha,
                                                 const float* __restrict__ xres,
                                                 void* __restrict__ outp) {
    __shared__ __align__(16) unsigned short Xs[4 * 132 * 32];   // 33,792 B, XOR-swizzled

    // XCD-contiguous remap (3072 = 8 * 384, bijective)
    int bid0 = blockIdx.x;
    int bid = (bid0 & 7) * 384 + (bid0 >> 3);

    int ob   = bid % 3;
    int wseg = (bid / 3) & 3;
    int hp   = (bid / 12) & 127;
    int n    = bid / 1536;
    int w0 = wseg << 7;
    int o0 = ob << 7;
    int h0 = hp << 1;

    int tid = threadIdx.x;
    int lane = tid & 63;
    int wv = tid >> 6;
    int wr = wv >> 1, wc = wv & 1;     // wr: output row h0+wr, wc: o-half
    int lg = lane >> 4, lm = lane & 15;

    const int KHt[13] = {0,0,0,0,0,1,1,1,1,1,2,2,2};
    const int KWt[13] = {0,1,2,3,4,0,1,2,3,4,0,1,2};

    f32x4 acc[32];
    #pragma unroll
    for (int i = 0; i < 32; ++i) acc[i] = (f32x4){0.f, 0.f, 0.f, 0.f};

    for (int ic = 0; ic < 12; ++ic) {
        __syncthreads();               // previous iteration's Xs readers done
        // stage 4 input rows (h0-2 .. h0+1) x 132 cols x 32 ch, swizzled
        #pragma unroll
        for (int it = 0; it < 9; ++it) {
            int ci = tid + it * 256;
            if (ci < 2112) {
                int r = ci / 528;
                int rem = ci - r * 528;
                int c = rem >> 2, q = rem & 3;
                int gr = h0 - 2 + r;
                int gw = w0 - 2 + c;
                int4v v = (int4v){0, 0, 0, 0};
                if ((unsigned)gr < HH && (unsigned)gw < WWD)
                    v = *(const int4v*)&in_nhwc[((n * HH + gr) * WWD + gw) * C_CH + ic * 32 + q * 8];
                int sidx = (r * 4224 + c * 32 + q * 8) ^ ((c & 7) << 3);
                *(int4v*)&Xs[sidx] = v;
            }
        }
        __syncthreads();

        #pragma unroll
        for (int t = 0; t < 13; ++t) {
            int kh = KHt[t], kw = KWt[t];
            // W fragments straight from global (coalesced 1KB per wave-instr, L1/L2-hot)
            const unsigned short* wb_base = wp + (((t * 12 + ic) * C_CH) + o0 + wc * 64) * 32;
            short8 wb[4];
            #pragma unroll
            for (int j = 0; j < 4; ++j)
                wb[j] = *(const short8*)&wb_base[(j * 16 + lm) * 32 + lg * 8];
            // X fragments from swizzled LDS (row wr+kh)
            short8 xa[8];
            #pragma unroll
            for (int f = 0; f < 8; ++f) {
                int cx = f * 16 + lm + kw;
                int sidx = ((wr + kh) * 4224 + cx * 32 + lg * 8) ^ ((cx & 7) << 3);
                xa[f] = *(const short8*)&Xs[sidx];
            }
            if (SECOND) {
                #pragma unroll
                for (int i = 0; i < 4; ++i)
                    #pragma unroll
                    for (int j = 0; j < 8; ++j)
                        acc[i * 8 + j] = __builtin_amdgcn_mfma_f32_16x16x32_bf16(wb[i], xa[j], acc[i * 8 + j], 0, 0, 0);
            } else {
                #pragma unroll
                for (int f = 0; f < 8; ++f)
                    #pragma unroll
                    for (int j = 0; j < 4; ++j)
                        acc[f * 4 + j] = __builtin_amdgcn_mfma_f32_16x16x32_bf16(xa[f], wb[j], acc[f * 4 + j], 0, 0, 0);
            }
        }
    }

    int h = h0 + wr;
    if (!SECOND) {
        // D[p][o]: p = w0 + f*16 + lg*4 + rr ; o = o0 + wc*64 + j*16 + lm
        unsigned short* y = (unsigned short*)outp;
        int pos_row = (n * HH + h) * WWD;
        #pragma unroll
        for (int j = 0; j < 4; ++j) {
            int o = o0 + wc * 64 + j * 16 + lm;
            float bo = bias[o], ao = alpha[o];
            #pragma unroll
            for (int f = 0; f < 8; ++f) {
                #pragma unroll
                for (int rr = 0; rr < 4; ++rr) {
                    int p = w0 + f * 16 + lg * 4 + rr;
                    float v = acc[f * 4 + j][rr] + bo;
                    v = v >= 0.f ? v : ao * v;
                    y[(pos_row + p) * C_CH + o] = f2bf(v);
                }
            }
        }
    } else {
        // D[o][p]: o = o0 + wc*64 + i*16 + lg*4 + rr ; w = w0 + j*16 + lm
        float* outf = (float*)outp;
        #pragma unroll
        for (int i = 0; i < 4; ++i) {
            #pragma unroll
            for (int rr = 0; rr < 4; ++rr) {
                int o = o0 + wc * 64 + i * 16 + lg * 4 + rr;
                float bo = bias[o], ao = alpha[o];
                #pragma unroll
                for (int j = 0; j < 8; ++j) {
                    int w = w0 + j * 16 + lm;
                    float v = acc[i * 8 + j][rr] + bo;
                    v = v >= 0.f ? v : ao * v;
                    int idx = ((n * C_CH + o) * HH + h) * WWD + w;
                    outf[idx] = v + xres[idx];
                }
            }
        }
    }
}

extern "C" void kernel_launch(void* const* d_in, const int* in_sizes, int n_in,
                              void* d_out, int out_size, void* d_ws, size_t ws_size,
                              hipStream_t stream) {
    const float* x  = (const float*)d_in[0];
    const float* w1 = (const float*)d_in[1];
    const float* b1 = (const float*)d_in[2];
    const float* a1 = (const float*)d_in[3];
    const float* w2 = (const float*)d_in[4];
    const float* b2 = (const float*)d_in[5];
    const float* a2 = (const float*)d_in[6];

    unsigned short* xc  = (unsigned short*)d_out;                       // 201,326,592 B scratch
    unsigned short* y   = (unsigned short*)d_ws;                        // 201,326,592 B
    unsigned short* wp1 = (unsigned short*)((char*)d_ws + 201326592u);  // 3,833,856 B
    unsigned short* wp2 = wp1 + 13 * 12 * C_CH * 32;                    // 3,833,856 B

    k_prepack<<<(13 * 12 * C_CH * 32 + 255) / 256, 256, 0, stream>>>(w1, w2, wp1, wp2);
    k_tobf16_nhwc<<<NN * HH * (WWD / 64), 256, 0, stream>>>(x, xc);
    k_conv<0><<<NN * (HH / 2) * (WWD / 128) * 3, 256, 0, stream>>>(xc, wp1, b1, a1, nullptr, (void*)y);
    k_conv<1><<<NN * (HH / 2) * (WWD / 128) * 3, 256, 0, stream>>>(y, wp2, b2, a2, x, (void*)d_out);
}

// Round 3
// 2011.381 us; speedup vs baseline: 2.1223x; 1.6294x over previous
//
#include <hip/hip_runtime.h>
#include <hip/hip_bf16.h>

// EntropyResidualBlock: y1 = prelu(maskconv(x,w1)+b1); y2 = prelu(maskconv(y1,w2)+b2); out = y2 + x
// 13 live taps: (0,kw0..4),(1,kw0..4),(2,0),(2,1),(2,2 group-causal i/24<=o/24).
// Implicit GEMM, mfma_f32_16x16x32_bf16.
//   conv1: D[p][o] = sum_t,i X[p+d(t)][i] * W1[t][i][o]   (A=X, B=W)
//   conv2: D[o][p] = sum_t,i W2[t][o][i] * Y[p+d(t)][i]   (A=W, B=Y)
// Round-3: halo-padded chunked layout [n][c/32][h+4][w+4][32] bf16 for X and Y ->
// staging is contiguous, bounds-check-free, via global_load_lds (16B), double-buffered,
// issues spread across taps (counted-vmcnt overlap). Linear LDS tile (contiguous 1KB
// ds_read_b128 per fragment -> zero bank conflicts). W prefetched 1 tap ahead in regs.
// Xc lives in d_out (dead before conv2 writes d_out); y + packed W in ws.
// ws need: 206,069,760 (y) + 2*3,833,856 (w) = 213,737,472 B.

#define C_CH 384
#define HH   256
#define WWD  512
#define NN   2
#define NC   12            // channel chunks of 32
#define PR   260           // padded rows  (h+2, 2 top + 2 bottom)
#define PC   516           // padded cols  (w+2)
#define ICS  (PR * PC * 32)    // shorts per (n, chunk) plane = 4,293,120
#define TCOLS 144          // staged cols (132 needed, padded to 36 KB = 36 wave-issues)
#define TSHORTS (4 * TCOLS * 32)   // 18432 shorts = 36,864 B per buffer

typedef __attribute__((ext_vector_type(8))) short short8;
typedef __attribute__((ext_vector_type(4))) float f32x4;

typedef const __attribute__((address_space(1))) void* gas_t;
typedef __attribute__((address_space(3))) void* las_t;

__device__ inline unsigned short f2bf(float f) {
    union { float f; unsigned int u; } v; v.f = f;
    unsigned int r = v.u + 0x7FFFu + ((v.u >> 16) & 1u);
    return (unsigned short)(r >> 16);
}

// ---------------- weights -> bf16 wp[t][ic][o][iq], masked ----------------
__global__ __launch_bounds__(256) void k_prepack(const float* __restrict__ w1, const float* __restrict__ w2,
                                                 unsigned short* __restrict__ wp1, unsigned short* __restrict__ wp2) {
    int idx = blockIdx.x * 256 + threadIdx.x;
    const int TOT = 13 * NC * C_CH * 32;
    if (idx >= TOT) return;
    int iq = idx & 31;
    int o  = (idx >> 5) % C_CH;
    int ic = (idx / (32 * C_CH)) % NC;
    int t  = idx / (32 * C_CH * NC);
    int i  = ic * 32 + iq;
    int kh = t < 5 ? 0 : (t < 10 ? 1 : 2);
    int kw = t < 5 ? t : (t < 10 ? t - 5 : t - 10);
    bool keep = (t != 12) || ((i / 24) <= (o / 24));
    int src = ((o * C_CH + i) * 5 + kh) * 5 + kw;
    wp1[idx] = keep ? f2bf(w1[src]) : (unsigned short)0;
    wp2[idx] = keep ? f2bf(w2[src]) : (unsigned short)0;
}

// ---------------- x NCHW fp32 -> padded chunked bf16 ----------------
__global__ __launch_bounds__(256) void k_repack_x(const float* __restrict__ x, unsigned short* __restrict__ xc) {
    int bid = blockIdx.x;              // 2*256*8 = 4096 blocks: 64 w x 384 c for one (n,h)
    int w0 = (bid & 7) << 6;
    int h  = (bid >> 3) & 255;
    int n  = bid >> 11;
    int wi = threadIdx.x & 63;
    int cq = threadIdx.x >> 6;         // 0..3
    int w  = w0 + wi;
    int inb = n * C_CH * HH * WWD + h * WWD + w;
    for (int cc = 0; cc < NC; ++cc) {
        int c0 = cc * 32 + cq * 8;
        short8 outv;
        #pragma unroll
        for (int k = 0; k < 8; ++k) {
            float f = x[inb + (c0 + k) * (HH * WWD)];
            outv[k] = (short)f2bf(f);
        }
        int oidx = (n * NC + cc) * ICS + (h + 2) * (PC * 32) + (w + 2) * 32 + cq * 8;
        *(short8*)&xc[oidx] = outv;
    }
}

// ---------------- masked conv via MFMA ----------------
// grid 3072; 256 threads / 4 waves (wr = h-row 0/1, wc = o-half).
template<int SECOND>
__global__ __launch_bounds__(256, 2) void k_conv(const unsigned short* __restrict__ in,   // padded chunked
                                                 const unsigned short* __restrict__ wp,
                                                 const float* __restrict__ bias,
                                                 const float* __restrict__ alpha,
                                                 const float* __restrict__ xres,
                                                 void* __restrict__ outp) {
    __shared__ __align__(16) unsigned short Xs[2][TSHORTS];   // 2 x 36,864 B, linear

    // grid decode: ob is SLOW; the 3 ob-blocks of a tile run consecutively on one XCD.
    int bid0 = blockIdx.x;
    int xcd = bid0 & 7;
    int j0  = bid0 >> 3;                 // 0..383
    int tile = xcd * 128 + j0 / 3;       // 0..1023
    int ob   = j0 % 3;
    int n    = tile >> 9;
    int hp   = (tile >> 2) & 127;
    int wseg = tile & 3;
    int w0 = wseg << 7, o0 = ob << 7, h0 = hp << 1;

    int tid = threadIdx.x;
    int lane = tid & 63;
    int wv = tid >> 6;
    int wr = wv >> 1, wc = wv & 1;
    int lg = lane >> 4, lm = lane & 15;

    // per-lane global offsets (shorts) for this thread's 9 staging issues
    int goff[9];
    #pragma unroll
    for (int it = 0; it < 9; ++it) {
        int k = wv * 9 + it;             // wave-issue index 0..35
        int s = k * 64 + lane;           // 16B slot 0..2303
        int r = s / 576;                 // 4 rows x 144 cols x 4 q = 576 slots/row
        int rem = s - r * 576;
        int c = rem >> 2, q = rem & 3;
        int ce = c < 132 ? c : 0;        // junk cols read col 0 (never consumed)
        goff[it] = ((h0 + r) * PC + (w0 + ce)) * 32 + q * 8;
    }

    f32x4 acc[32];
    #pragma unroll
    for (int i = 0; i < 32; ++i) acc[i] = (f32x4){0.f, 0.f, 0.f, 0.f};

    // prologue: stage ic=0 into buf 0
    {
        const unsigned short* gbase = in + (n * NC + 0) * ICS;
        #pragma unroll
        for (int it = 0; it < 9; ++it) {
            const unsigned short* gp = gbase + goff[it];
            unsigned short* lp = &Xs[0][(wv * 9 + it) * 512];
            __builtin_amdgcn_global_load_lds((gas_t)gp, (las_t)lp, 16, 0, 0);
        }
    }
    __syncthreads();

    for (int ic = 0; ic < NC; ++ic) {
        int buf = ic & 1;
        const unsigned short* gnext = in + (n * NC + (ic + 1)) * ICS;
        // W for tap 0
        short8 wb[4], wbn[4];
        {
            const unsigned short* wb0 = wp + ((0 * NC + ic) * C_CH + o0 + wc * 64) * 32;
            #pragma unroll
            for (int j = 0; j < 4; ++j) wb[j] = *(const short8*)&wb0[(j * 16 + lm) * 32 + lg * 8];
        }
        #pragma unroll
        for (int t = 0; t < 13; ++t) {
            if (t < 12) {   // prefetch next tap's W
                const unsigned short* wbp = wp + (((t + 1) * NC + ic) * C_CH + o0 + wc * 64) * 32;
                #pragma unroll
                for (int j = 0; j < 4; ++j) wbn[j] = *(const short8*)&wbp[(j * 16 + lm) * 32 + lg * 8];
            }
            if (t < 9) {    // spread next-ic staging across taps 0..8
                if (ic < NC - 1) {
                    const unsigned short* gp = gnext + goff[t];
                    unsigned short* lp = &Xs[buf ^ 1][(wv * 9 + t) * 512];
                    __builtin_amdgcn_global_load_lds((gas_t)gp, (las_t)lp, 16, 0, 0);
                }
            }
            int kh = t < 5 ? 0 : (t < 10 ? 1 : 2);
            int kw = t < 5 ? t : (t < 10 ? t - 5 : t - 10);
            short8 xa[8];
            #pragma unroll
            for (int f = 0; f < 8; ++f) {
                int cx = f * 16 + lm + kw;
                xa[f] = *(const short8*)&Xs[buf][(wr + kh) * (TCOLS * 32) + cx * 32 + lg * 8];
            }
            if (SECOND) {
                #pragma unroll
                for (int i = 0; i < 4; ++i)
                    #pragma unroll
                    for (int j = 0; j < 8; ++j)
                        acc[i * 8 + j] = __builtin_amdgcn_mfma_f32_16x16x32_bf16(wb[i], xa[j], acc[i * 8 + j], 0, 0, 0);
            } else {
                #pragma unroll
                for (int f = 0; f < 8; ++f)
                    #pragma unroll
                    for (int j = 0; j < 4; ++j)
                        acc[f * 4 + j] = __builtin_amdgcn_mfma_f32_16x16x32_bf16(xa[f], wb[j], acc[f * 4 + j], 0, 0, 0);
            }
            if (t < 12) {
                #pragma unroll
                for (int j = 0; j < 4; ++j) wb[j] = wbn[j];
            }
        }
        __syncthreads();   // all waves done with buf; next-ic loads (issued >=4 taps ago) drained
    }

    int h = h0 + wr;
    if (!SECOND) {
        // write y in padded chunked layout: [(n*NC+oc)][h+2][w+2][32]
        unsigned short* y = (unsigned short*)outp;
        #pragma unroll
        for (int j = 0; j < 4; ++j) {
            int o = o0 + wc * 64 + j * 16 + lm;
            float bo = bias[o], ao = alpha[o];
            int base = (n * NC + (o >> 5)) * ICS + (h + 2) * (PC * 32) + (o & 31);
            #pragma unroll
            for (int f = 0; f < 8; ++f) {
                #pragma unroll
                for (int rr = 0; rr < 4; ++rr) {
                    int p = f * 16 + lg * 4 + rr;
                    float v = acc[f * 4 + j][rr] + bo;
                    v = v >= 0.f ? v : ao * v;
                    y[base + (w0 + p + 2) * 32] = f2bf(v);
                }
            }
        }
    } else {
        // D[o][p] -> NCHW fp32 + residual
        float* outf = (float*)outp;
        #pragma unroll
        for (int i = 0; i < 4; ++i) {
            #pragma unroll
            for (int rr = 0; rr < 4; ++rr) {
                int o = o0 + wc * 64 + i * 16 + lg * 4 + rr;
                float bo = bias[o], ao = alpha[o];
                #pragma unroll
                for (int j = 0; j < 8; ++j) {
                    int w = w0 + j * 16 + lm;
                    float v = acc[i * 8 + j][rr] + bo;
                    v = v >= 0.f ? v : ao * v;
                    int idx = ((n * C_CH + o) * HH + h) * WWD + w;
                    outf[idx] = v + xres[idx];
                }
            }
        }
    }
}

extern "C" void kernel_launch(void* const* d_in, const int* in_sizes, int n_in,
                              void* d_out, int out_size, void* d_ws, size_t ws_size,
                              hipStream_t stream) {
    const float* x  = (const float*)d_in[0];
    const float* w1 = (const float*)d_in[1];
    const float* b1 = (const float*)d_in[2];
    const float* a1 = (const float*)d_in[3];
    const float* w2 = (const float*)d_in[4];
    const float* b2 = (const float*)d_in[5];
    const float* a2 = (const float*)d_in[6];

    const size_t PLANE_SHORTS = (size_t)NN * NC * ICS;          // 103,034,880 shorts
    unsigned short* xc  = (unsigned short*)d_out;               // 206,069,760 B (of 402 MB d_out)
    unsigned short* yb  = (unsigned short*)d_ws;                // 206,069,760 B
    unsigned short* wp1 = yb + PLANE_SHORTS;                    // 3,833,856 B
    unsigned short* wp2 = wp1 + 13 * NC * C_CH * 32;            // 3,833,856 B

    // zero halos (whole buffers for simplicity)
    hipMemsetAsync(xc, 0, PLANE_SHORTS * 2, stream);
    hipMemsetAsync(yb, 0, PLANE_SHORTS * 2, stream);

    k_prepack<<<(13 * NC * C_CH * 32 + 255) / 256, 256, 0, stream>>>(w1, w2, wp1, wp2);
    k_repack_x<<<NN * HH * (WWD / 64), 256, 0, stream>>>(x, xc);
    k_conv<0><<<3072, 256, 0, stream>>>(xc, wp1, b1, a1, nullptr, (void*)yb);
    k_conv<1><<<3072, 256, 0, stream>>>(yb, wp2, b2, a2, x, (void*)d_out);
}

// Round 4
// 1922.061 us; speedup vs baseline: 2.2209x; 1.0465x over previous
//
#include <hip/hip_runtime.h>
#include <hip/hip_bf16.h>

// EntropyResidualBlock: y1 = prelu(maskconv(x,w1)+b1); y2 = prelu(maskconv(y1,w2)+b2); out = y2 + x
// 13 live taps. Implicit GEMM with mfma_f32_32x32x16_bf16 (2495 TF ceiling vs 2075 for 16x16).
//   conv1: D[p][o] = sum X[p+d(t)][i]*W1[t][i][o]  (A=X,B=W);  conv2: D[o][p] (A=W,B=Y).
// Layouts: X/Y packed [n][kc=24 x 16ch][h+4][w+4][16] bf16 (halo-padded);
//          W packed [t][kc][o][16] bf16 (masked). All fragment reads = linear 1KB/wave.
// Per block: 2 h-rows x 128 w x 128 o, 4 waves (wr=row, wc=o-half); per wave 128p x 64o,
// acc = 4x2 f32x16 (128 AGPR). 26 k-steps/ic: xa ds_read 1 step ahead (2 sets),
// wb global 2 steps ahead (3-ring), setprio around MFMA cluster. X staged to LDS via
// global_load_lds (16B), double-buffered, all 9 issues right after barrier.
// ws: [ Y : 206069760 B ][ Wp1 : 3833856 B ][ Wp2 : 3833856 B ]; Xc in d_out (dead before conv2).

#define C_CH 384
#define HH   256
#define WWD  512
#define NN   2
#define NKC  24                    // 16-channel chunks
#define PR   260
#define PC   516
#define ICS16 (PR * PC * 16)       // shorts per (n,kc) plane = 2,146,560
#define TCOLS 144
#define PLANE_SH (4 * TCOLS * 16)  // 9216 shorts per kc sub-plane in LDS
#define TSH (2 * PLANE_SH)         // 18432 shorts per LDS buffer (36,864 B)

typedef __attribute__((ext_vector_type(8)))  short short8;
typedef __attribute__((ext_vector_type(16))) float f32x16;
typedef __attribute__((ext_vector_type(4)))  int   int4v;

typedef const __attribute__((address_space(1))) void* gas_t;
typedef __attribute__((address_space(3))) void* las_t;

__device__ inline unsigned short f2bf(float f) {
    union { float f; unsigned int u; } v; v.f = f;
    unsigned int r = v.u + 0x7FFFu + ((v.u >> 16) & 1u);
    return (unsigned short)(r >> 16);
}

// ---------------- weights -> bf16 wp[t][kc][o][16], masked ----------------
__global__ __launch_bounds__(256) void k_prepack(const float* __restrict__ w1, const float* __restrict__ w2,
                                                 unsigned short* __restrict__ wp1, unsigned short* __restrict__ wp2) {
    int idx = blockIdx.x * 256 + threadIdx.x;
    const int TOT = 13 * NKC * C_CH * 16;
    if (idx >= TOT) return;
    int iq = idx & 15;
    int o  = (idx >> 4) % C_CH;
    int kc = (idx / (16 * C_CH)) % NKC;
    int t  = idx / (16 * C_CH * NKC);
    int i  = kc * 16 + iq;
    int kh = t < 5 ? 0 : (t < 10 ? 1 : 2);
    int kw = t < 5 ? t : (t < 10 ? t - 5 : t - 10);
    bool keep = (t != 12) || ((i / 24) <= (o / 24));
    int src = ((o * C_CH + i) * 5 + kh) * 5 + kw;
    wp1[idx] = keep ? f2bf(w1[src]) : (unsigned short)0;
    wp2[idx] = keep ? f2bf(w2[src]) : (unsigned short)0;
}

// ---------------- x NCHW fp32 -> padded 16ch-chunked bf16 ----------------
__global__ __launch_bounds__(256) void k_repack_x(const float* __restrict__ x, unsigned short* __restrict__ xc) {
    int bid = blockIdx.x;              // 4096 blocks: 64 w x 384 c for one (n,h)
    int w0 = (bid & 7) << 6;
    int h  = (bid >> 3) & 255;
    int n  = bid >> 11;
    int wi = threadIdx.x & 63;
    int cq = threadIdx.x >> 6;         // 0..3 (8 channels each)
    int w  = w0 + wi;
    int inb = n * C_CH * HH * WWD + h * WWD + w;
    for (int cc = 0; cc < 12; ++cc) {
        int c0 = cc * 32 + cq * 8;
        short8 outv;
        #pragma unroll
        for (int k = 0; k < 8; ++k) {
            float f = x[inb + (c0 + k) * (HH * WWD)];
            outv[k] = (short)f2bf(f);
        }
        int kc = cc * 2 + (cq >> 1);
        int oidx = (n * NKC + kc) * ICS16 + ((h + 2) * PC + (w + 2)) * 16 + (cq & 1) * 8;
        *(short8*)&xc[oidx] = outv;
    }
}

// ---------------- masked conv via 32x32x16 MFMA ----------------
// grid 3072; 256 threads / 4 waves (wr = h-row 0/1, wc = o-half).
template<int SECOND>
__global__ __launch_bounds__(256, 2) void k_conv(const unsigned short* __restrict__ in,   // packed
                                                 const unsigned short* __restrict__ wp,
                                                 const float* __restrict__ bias,
                                                 const float* __restrict__ alpha,
                                                 const float* __restrict__ xres,
                                                 void* __restrict__ outp) {
    __shared__ __align__(16) unsigned short Xs[2][TSH];   // 2 x 36,864 B

    // ob slow within XCD chunk: 3 ob-blocks of one tile run consecutively on one XCD
    int bid0 = blockIdx.x;
    int xcd = bid0 & 7;
    int j0  = bid0 >> 3;
    int tile = xcd * 128 + j0 / 3;
    int ob   = j0 % 3;
    int n    = tile >> 9;
    int hp   = (tile >> 2) & 127;
    int wseg = tile & 3;
    int w0 = wseg << 7, o0 = ob << 7, h0 = hp << 1;

    int tid = threadIdx.x;
    int lane = tid & 63;
    int wv = tid >> 6;
    int wr = wv >> 1, wc = wv & 1;
    int lo5 = lane & 31, hi = lane >> 5;

    // staging: 36 wave-issues per buffer, 9 per wave; per-lane global offsets
    int goff[9];
    #pragma unroll
    for (int it = 0; it < 9; ++it) {
        int k = wv * 9 + it;
        int plane = k / 18;
        int s = (k % 18) * 64 + lane;
        int r = s / 288;
        int rem = s - r * 288;
        int col = rem >> 1, h16 = rem & 1;
        goff[it] = plane * ICS16 + ((h0 + r) * PC + (w0 + col)) * 16 + h16 * 8;
    }

    const int KH[13] = {0,0,0,0,0,1,1,1,1,1,2,2,2};
    const int KW[13] = {0,1,2,3,4,0,1,2,3,4,0,1,2};

    f32x16 acc[4][2];
    #pragma unroll
    for (int pt = 0; pt < 4; ++pt)
        #pragma unroll
        for (int ot = 0; ot < 2; ++ot)
            #pragma unroll
            for (int r = 0; r < 16; ++r) acc[pt][ot][r] = 0.f;

    const unsigned short* gbase_n = in + (size_t)n * NKC * ICS16;

    // prologue: stage ic=0 into buf 0
    #pragma unroll
    for (int it = 0; it < 9; ++it) {
        const unsigned short* gp = gbase_n + goff[it];
        unsigned short* lp = &Xs[0][(wv * 9 + it) * 512];
        __builtin_amdgcn_global_load_lds((gas_t)gp, (las_t)lp, 16, 0, 0);
    }
    __syncthreads();

#define LOAD_XA(dst, u) do {                                              \
        int t_ = (u) >> 1, hf_ = (u) & 1;                                 \
        int so_ = hf_ * PLANE_SH + (wr + KH[t_]) * (TCOLS * 16)           \
                + (lo5 + KW[t_]) * 16 + hi * 8;                           \
        _Pragma("unroll")                                                 \
        for (int pt_ = 0; pt_ < 4; ++pt_)                                 \
            (dst)[pt_] = *(const short8*)&xs[so_ + pt_ * 512];            \
    } while (0)

#define LOAD_WB(dst, u) do {                                              \
        int t_ = (u) >> 1, hf_ = (u) & 1;                                 \
        const unsigned short* wb_ = wp +                                  \
            (size_t)((t_ * NKC + ic * 2 + hf_) * C_CH + o0 + wc * 64) * 16; \
        _Pragma("unroll")                                                 \
        for (int ot_ = 0; ot_ < 2; ++ot_)                                 \
            (dst)[ot_] = *(const short8*)&wb_[(ot_ * 32 + lo5) * 16 + hi * 8]; \
    } while (0)

    for (int ic = 0; ic < 12; ++ic) {
        int buf = ic & 1;
        const unsigned short* xs = &Xs[buf][0];
        // stage next ic immediately (queue drained by barrier; one early drain per ic)
        if (ic < 11) {
            const unsigned short* gb = gbase_n + (size_t)(ic + 1) * 2 * ICS16;
            #pragma unroll
            for (int it = 0; it < 9; ++it) {
                const unsigned short* gp = gb + goff[it];
                unsigned short* lp = &Xs[buf ^ 1][(wv * 9 + it) * 512];
                __builtin_amdgcn_global_load_lds((gas_t)gp, (las_t)lp, 16, 0, 0);
            }
        }

        short8 xa[2][4];
        short8 wb[3][2];
        LOAD_XA(xa[0], 0);
        LOAD_WB(wb[0], 0);
        LOAD_WB(wb[1], 1);

        #pragma unroll
        for (int s2 = 0; s2 < 26; ++s2) {
            if (s2 + 2 < 26) LOAD_WB(wb[(s2 + 2) % 3], s2 + 2);
            if (s2 + 1 < 26) LOAD_XA(xa[(s2 + 1) & 1], s2 + 1);
            __builtin_amdgcn_s_setprio(1);
            #pragma unroll
            for (int pt = 0; pt < 4; ++pt)
                #pragma unroll
                for (int ot = 0; ot < 2; ++ot) {
                    if (SECOND)
                        acc[pt][ot] = __builtin_amdgcn_mfma_f32_32x32x16_bf16(
                            wb[s2 % 3][ot], xa[s2 & 1][pt], acc[pt][ot], 0, 0, 0);
                    else
                        acc[pt][ot] = __builtin_amdgcn_mfma_f32_32x32x16_bf16(
                            xa[s2 & 1][pt], wb[s2 % 3][ot], acc[pt][ot], 0, 0, 0);
                }
            __builtin_amdgcn_s_setprio(0);
        }
        __syncthreads();
    }
#undef LOAD_XA
#undef LOAD_WB

    int h = h0 + wr;
    if (!SECOND) {
        // D[p][o]: p = pt*32 + (reg&3)+8*(reg>>2)+4*hi ; o = o0+wc*64+ot*32+lo5
        unsigned short* y = (unsigned short*)outp;
        #pragma unroll
        for (int ot = 0; ot < 2; ++ot) {
            int o = o0 + wc * 64 + ot * 32 + lo5;
            float bo = bias[o], ao = alpha[o];
            int kc = o >> 4;
            int o15 = o & 15;
            size_t base = (size_t)(n * NKC + kc) * ICS16 + ((h + 2) * PC + (w0 + 2)) * 16 + o15;
            #pragma unroll
            for (int pt = 0; pt < 4; ++pt) {
                #pragma unroll
                for (int reg = 0; reg < 16; ++reg) {
                    int p = pt * 32 + (reg & 3) + 8 * (reg >> 2) + 4 * hi;
                    float v = acc[pt][ot][reg] + bo;
                    v = v >= 0.f ? v : ao * v;
                    y[base + (size_t)p * 16] = f2bf(v);
                }
            }
        }
    } else {
        // D[o][p]: o = o0+wc*64+ot*32+(reg&3)+8*(reg>>2)+4*hi ; w = w0+pt*32+lo5
        float* outf = (float*)outp;
        #pragma unroll
        for (int ot = 0; ot < 2; ++ot) {
            #pragma unroll
            for (int reg = 0; reg < 16; ++reg) {
                int o = o0 + wc * 64 + ot * 32 + (reg & 3) + 8 * (reg >> 2) + 4 * hi;
                float bo = bias[o], ao = alpha[o];
                #pragma unroll
                for (int pt = 0; pt < 4; ++pt) {
                    int w = w0 + pt * 32 + lo5;
                    float v = acc[pt][ot][reg] + bo;
                    v = v >= 0.f ? v : ao * v;
                    size_t idx = (size_t)((n * C_CH + o) * HH + h) * WWD + w;
                    outf[idx] = v + xres[idx];
                }
            }
        }
    }
}

extern "C" void kernel_launch(void* const* d_in, const int* in_sizes, int n_in,
                              void* d_out, int out_size, void* d_ws, size_t ws_size,
                              hipStream_t stream) {
    const float* x  = (const float*)d_in[0];
    const float* w1 = (const float*)d_in[1];
    const float* b1 = (const float*)d_in[2];
    const float* a1 = (const float*)d_in[3];
    const float* w2 = (const float*)d_in[4];
    const float* b2 = (const float*)d_in[5];
    const float* a2 = (const float*)d_in[6];

    const size_t PLANE_SHORTS = (size_t)NN * NKC * ICS16;       // 103,034,880 shorts
    unsigned short* xc  = (unsigned short*)d_out;               // 206,069,760 B scratch in d_out
    unsigned short* yb  = (unsigned short*)d_ws;                // 206,069,760 B
    unsigned short* wp1 = yb + PLANE_SHORTS;                    // 3,833,856 B
    unsigned short* wp2 = wp1 + 13 * NKC * C_CH * 16;           // 3,833,856 B

    hipMemsetAsync(xc, 0, PLANE_SHORTS * 2, stream);
    hipMemsetAsync(yb, 0, PLANE_SHORTS * 2, stream);

    k_prepack<<<(13 * NKC * C_CH * 16 + 255) / 256, 256, 0, stream>>>(w1, w2, wp1, wp2);
    k_repack_x<<<NN * HH * (WWD / 64), 256, 0, stream>>>(x, xc);
    k_conv<0><<<3072, 256, 0, stream>>>(xc, wp1, b1, a1, nullptr, (void*)yb);
    k_conv<1><<<3072, 256, 0, stream>>>(yb, wp2, b2, a2, x, (void*)d_out);
}